// Round 5
// baseline (274.698 us; speedup 1.0000x reference)
//
#include <hip/hip_runtime.h>
#include <stdint.h>

typedef __attribute__((ext_vector_type(4))) float f32x4;
typedef __attribute__((ext_vector_type(8))) short bf16x8;

#define MFMA(a, b, c) __builtin_amdgcn_mfma_f32_16x16x32_bf16(a, b, c, 0, 0, 0)

__device__ __forceinline__ short f2b(float f) {
    uint32_t u = __builtin_bit_cast(uint32_t, f);
    u += 0x7fffu + ((u >> 16) & 1u);
    return (short)(u >> 16);
}

// ---------- cast [Wq;Wk;Wv;Wo] (fp32, each [256][256]) -> Wall bf16 [1024][256]
__global__ void k_cast_w(const float* __restrict__ Wq, const float* __restrict__ Wk,
                         const float* __restrict__ Wv, const float* __restrict__ Wo,
                         short* __restrict__ Wall) {
    int idx = blockIdx.x * 256 + threadIdx.x;   // grid = 1024 blocks
    int row = idx >> 8, col = idx & 255;
    float v;
    if (row < 256)      v = Wq[row * 256 + col];
    else if (row < 512) v = Wk[(row - 256) * 256 + col];
    else if (row < 768) v = Wv[(row - 512) * 256 + col];
    else                v = Wo[(row - 768) * 256 + col];
    Wall[idx] = f2b(v);
}

// ---------- transpose+cast x fp32 [256][2304] -> xt bf16 [2304][256]
__global__ void k_transpose_x(const float* __restrict__ x, short* __restrict__ xt) {
    __shared__ float tile[64][65];
    int pbase = blockIdx.x * 64, cbase = blockIdx.y * 64;  // grid (36,4)
    int tx = threadIdx.x & 63, tq = threadIdx.x >> 6;
    #pragma unroll
    for (int r = 0; r < 16; r++) {
        int row = tq * 16 + r;
        tile[row][tx] = x[(cbase + row) * 2304 + pbase + tx];
    }
    __syncthreads();
    #pragma unroll
    for (int r = 0; r < 16; r++) {
        int prow = tq * 16 + r;
        xt[(pbase + prow) * 256 + cbase + tx] = f2b(tile[tx][prow]);
    }
}

// ---------- QKV projection: C[768][2304] = Wall[0:768] @ x ; scatter to Qf/Kf/Vt
// Qf[n][64] bf16 (pre-scaled 1/8), Kf[n][64] bf16, Vt[64][9216] bf16, n = p*4+h
__global__ __launch_bounds__(256) void k_gemm_qkv(
    const short* __restrict__ Wall, const short* __restrict__ xt,
    const float* __restrict__ bq, const float* __restrict__ bk, const float* __restrict__ bv,
    short* __restrict__ Qf, short* __restrict__ Kf, short* __restrict__ Vt) {
    int t = threadIdx.x, wave = t >> 6, lane = t & 63, lr = lane & 15, lg = lane >> 4;
    int obase = blockIdx.x * 64 + wave * 16;   // grid.x = 12
    int pbase = blockIdx.y * 64;               // grid.y = 36
    const short* arow  = Wall + (obase + lr) * 256 + lg * 8;
    const short* brow0 = xt + (pbase +  0 + lr) * 256 + lg * 8;
    const short* brow1 = xt + (pbase + 16 + lr) * 256 + lg * 8;
    const short* brow2 = xt + (pbase + 32 + lr) * 256 + lg * 8;
    const short* brow3 = xt + (pbase + 48 + lr) * 256 + lg * 8;
    f32x4 acc0 = {0,0,0,0}, acc1 = {0,0,0,0}, acc2 = {0,0,0,0}, acc3 = {0,0,0,0};
    #pragma unroll
    for (int ks = 0; ks < 8; ks++) {
        bf16x8 a = *(const bf16x8*)(arow + ks * 32);
        acc0 = MFMA(a, *(const bf16x8*)(brow0 + ks * 32), acc0);
        acc1 = MFMA(a, *(const bf16x8*)(brow1 + ks * 32), acc1);
        acc2 = MFMA(a, *(const bf16x8*)(brow2 + ks * 32), acc2);
        acc3 = MFMA(a, *(const bf16x8*)(brow3 + ks * 32), acc3);
    }
    int w_idx = obase >> 8;  // 0=q 1=k 2=v, uniform per block
    const float* bias = (w_idx == 0) ? bq : (w_idx == 1) ? bk : bv;
    f32x4 accs[4] = {acc0, acc1, acc2, acc3};
    #pragma unroll
    for (int i = 0; i < 4; i++) {
        int o = obase + 4 * lg + i;
        int oo = o & 255;
        float b = bias[oo];
        int h = oo >> 6, d = oo & 63;
        #pragma unroll
        for (int ct = 0; ct < 4; ct++) {
            int p = pbase + ct * 16 + lr;
            float val = accs[ct][i] + b;
            int n = p * 4 + h;
            if (w_idx == 0)      Qf[n * 64 + d] = f2b(val * 0.125f);
            else if (w_idx == 1) Kf[n * 64 + d] = f2b(val);
            else                 Vt[d * 9216 + n] = f2b(val);
        }
    }
}

// ---------- flash attention: N=9216, d=64. Grid (576 qblocks, 4 kvblocks).
// Block = 8 waves x 512 thr; owns 16 queries x 2304 keys; wave w handles keys
// [(kb*8+w)*288, +288) in 9 tiles of 32.
// __launch_bounds__(512, 2): 2nd arg is BLOCKS/CU (CUDA semantics) -> 2 blocks/CU
// -> 128 VGPR/wave budget. Live state ~90 VGPR fits => NO scratch spills (the
// r1-r4 killer: 40-64 VGPR forced per-iteration scratch round-trips).
// Swapped QK^T (mfma(K,Q)=S^T, permuted K rows) => S^T regs are the PV B-frag.
// Denominator via ones-MFMA (no sum shfls); max-reduce via 3 parallel shfl_xor.
__global__ __launch_bounds__(512, 2) void k_attn(
    const short* __restrict__ Qf, const short* __restrict__ Kf,
    const short* __restrict__ Vt,
    float* __restrict__ pm, float* __restrict__ ps, float* __restrict__ pacc) {
    __shared__ float lds_m[8][16];
    __shared__ float lds_s[8][16];
    __shared__ float lds_acc[64][16];
    int t = threadIdx.x, wave = t >> 6, lane = t & 63, lr = lane & 15, lg = lane >> 4;
    int qbase = blockIdx.x * 16;   // grid.x = 576
    int kb = blockIdx.y;           // grid.y = 4
    #pragma unroll
    for (int r = 0; r < 2; r++) ((float*)lds_acc)[t + 512 * r] = 0.f;

    const short* qrow = Qf + (qbase + lr) * 64 + lg * 8;
    bf16x8 q0 = *(const bf16x8*)(qrow);
    bf16x8 q1 = *(const bf16x8*)(qrow + 32);

    bf16x8 ones;
    #pragma unroll
    for (int i = 0; i < 8; i++) ones[i] = (short)0x3F80;   // bf16 1.0

    float mA = -1e30f;
    f32x4 zv = {0,0,0,0};
    f32x4 acc[4];
    #pragma unroll
    for (int i = 0; i < 4; i++) acc[i] = zv;
    f32x4 sacc = zv;

    int perm = (lr & 3) + 8 * (lr >> 2);   // K-row permutation: st regs -> B-frag layout
    int jstart = (kb * 8 + wave) * 288;
    const short* kbase_p = Kf + (jstart + perm) * 64 + lg * 8;
    const short* vbase_p = Vt + lr * 9216 + jstart + lg * 8;

    for (int it = 0; it < 9; it++) {
        // K tile (2KB contiguous region per 16 rows); dies right after QK MFMAs
        const short* kp = kbase_p + it * (32 * 64);
        bf16x8 k00 = *(const bf16x8*)(kp);
        bf16x8 k01 = *(const bf16x8*)(kp + 32);
        bf16x8 k10 = *(const bf16x8*)(kp + 256);       // +4 key rows
        bf16x8 k11 = *(const bf16x8*)(kp + 256 + 32);

        // QK^T (S^T): rows = keys (perm'd), cols = queries
        f32x4 st0 = MFMA(k00, q0, zv); st0 = MFMA(k01, q1, st0);
        f32x4 st1 = MFMA(k10, q0, zv); st1 = MFMA(k11, q1, st1);

        // online softmax: max over 32 keys for q = qbase+lr
        float tm = fmaxf(fmaxf(fmaxf(st0[0], st0[1]), fmaxf(st0[2], st0[3])),
                         fmaxf(fmaxf(st1[0], st1[1]), fmaxf(st1[2], st1[3])));
        float ta = __shfl_xor(tm, 16);
        float tb = __shfl_xor(tm, 32);
        float tc = __shfl_xor(tm, 48);
        tm = fmaxf(fmaxf(tm, ta), fmaxf(tb, tc));
        float mn = fmaxf(mA, tm);
        float sc = __expf(mA - mn);
        mA = mn;
        bf16x8 pb;
        pb[0] = f2b(__expf(st0[0] - mn)); pb[1] = f2b(__expf(st0[1] - mn));
        pb[2] = f2b(__expf(st0[2] - mn)); pb[3] = f2b(__expf(st0[3] - mn));
        pb[4] = f2b(__expf(st1[0] - mn)); pb[5] = f2b(__expf(st1[1] - mn));
        pb[6] = f2b(__expf(st1[2] - mn)); pb[7] = f2b(__expf(st1[3] - mn));

        // V tile loaded after softmax (shortens live ranges; TLP covers latency)
        const short* vp = vbase_p + it * 32;
        bf16x8 v0 = *(const bf16x8*)(vp);
        bf16x8 v1 = *(const bf16x8*)(vp + 16 * 9216);
        bf16x8 v2 = *(const bf16x8*)(vp + 32 * 9216);
        bf16x8 v3 = *(const bf16x8*)(vp + 48 * 9216);

        // PV + denominator (ones-MFMA); rescale accumulators by sc
        acc[0] = MFMA(v0, pb, acc[0] * sc);
        acc[1] = MFMA(v1, pb, acc[1] * sc);
        acc[2] = MFMA(v2, pb, acc[2] * sc);
        acc[3] = MFMA(v3, pb, acc[3] * sc);
        sacc   = MFMA(ones, pb, sacc * sc);
    }

    // ---- combine the 8 waves within the block
    if (lane < 16) {           // lg==0: sacc[0] = s[q=lr]
        lds_m[wave][lr] = mA;
        lds_s[wave][lr] = sacc[0];
    }
    __syncthreads();
    float mg = lds_m[0][lr];
    #pragma unroll
    for (int w = 1; w < 8; w++) mg = fmaxf(mg, lds_m[w][lr]);
    float fA = __expf(mA - mg);
    #pragma unroll
    for (int dvt = 0; dvt < 4; dvt++) {
        #pragma unroll
        for (int i = 0; i < 4; i++)
            atomicAdd(&lds_acc[dvt * 16 + 4 * lg + i][lr], acc[dvt][i] * fA);
    }
    __syncthreads();
    int pidx = kb * 576 + blockIdx.x;
    if (t < 16) {
        int q = t;
        float mgq = lds_m[0][q];
        #pragma unroll
        for (int w = 1; w < 8; w++) mgq = fmaxf(mgq, lds_m[w][q]);
        float S = 0.f;
        #pragma unroll
        for (int w = 0; w < 8; w++) S += lds_s[w][q] * __expf(lds_m[w][q] - mgq);
        pm[pidx * 16 + q] = mgq;
        ps[pidx * 16 + q] = S;
    }
    #pragma unroll
    for (int r = 0; r < 2; r++) {
        int idx = t + 512 * r;
        pacc[pidx * 1024 + idx] = ((float*)lds_acc)[idx];
    }
}

// ---------- combine 4 KV-split partials -> Of bf16 [2304][256]
__global__ __launch_bounds__(256) void k_attn_combine(
    const float* __restrict__ pm, const float* __restrict__ ps,
    const float* __restrict__ pacc, short* __restrict__ Of) {
    int qb = blockIdx.x, t = threadIdx.x;   // grid = 576
    #pragma unroll
    for (int r = 0; r < 4; r++) {
        int idx = t + 256 * r;              // 0..1023
        int dv = idx >> 4, q = idx & 15;
        float m0 = pm[(0 * 576 + qb) * 16 + q], m1 = pm[(1 * 576 + qb) * 16 + q];
        float m2 = pm[(2 * 576 + qb) * 16 + q], m3 = pm[(3 * 576 + qb) * 16 + q];
        float mg = fmaxf(fmaxf(m0, m1), fmaxf(m2, m3));
        float e0 = __expf(m0 - mg), e1 = __expf(m1 - mg);
        float e2 = __expf(m2 - mg), e3 = __expf(m3 - mg);
        float S = ps[(0 * 576 + qb) * 16 + q] * e0 + ps[(1 * 576 + qb) * 16 + q] * e1
                + ps[(2 * 576 + qb) * 16 + q] * e2 + ps[(3 * 576 + qb) * 16 + q] * e3;
        float O = pacc[(0 * 576 + qb) * 1024 + idx] * e0
                + pacc[(1 * 576 + qb) * 1024 + idx] * e1
                + pacc[(2 * 576 + qb) * 1024 + idx] * e2
                + pacc[(3 * 576 + qb) * 1024 + idx] * e3;
        int n = qb * 16 + q, p = n >> 2, hh = n & 3;
        Of[p * 256 + hh * 64 + dv] = f2b(O / S);
    }
}

// ---------- output projection: out[256][2304] = Wo @ Of^T + bo (fp32 out, NCHW)
__global__ __launch_bounds__(256) void k_gemm_out(
    const short* __restrict__ Wo_bf, const short* __restrict__ Of,
    const float* __restrict__ bo, float* __restrict__ out) {
    int t = threadIdx.x, wave = t >> 6, lane = t & 63, lr = lane & 15, lg = lane >> 4;
    int obase = blockIdx.x * 64 + wave * 16;   // grid.x = 4
    int pbase = blockIdx.y * 64;               // grid.y = 36
    const short* arow  = Wo_bf + (obase + lr) * 256 + lg * 8;
    const short* brow0 = Of + (pbase +  0 + lr) * 256 + lg * 8;
    const short* brow1 = Of + (pbase + 16 + lr) * 256 + lg * 8;
    const short* brow2 = Of + (pbase + 32 + lr) * 256 + lg * 8;
    const short* brow3 = Of + (pbase + 48 + lr) * 256 + lg * 8;
    f32x4 acc0 = {0,0,0,0}, acc1 = {0,0,0,0}, acc2 = {0,0,0,0}, acc3 = {0,0,0,0};
    #pragma unroll
    for (int ks = 0; ks < 8; ks++) {
        bf16x8 a = *(const bf16x8*)(arow + ks * 32);
        acc0 = MFMA(a, *(const bf16x8*)(brow0 + ks * 32), acc0);
        acc1 = MFMA(a, *(const bf16x8*)(brow1 + ks * 32), acc1);
        acc2 = MFMA(a, *(const bf16x8*)(brow2 + ks * 32), acc2);
        acc3 = MFMA(a, *(const bf16x8*)(brow3 + ks * 32), acc3);
    }
    f32x4 accs[4] = {acc0, acc1, acc2, acc3};
    #pragma unroll
    for (int i = 0; i < 4; i++) {
        int o = obase + 4 * lg + i;
        float b = bo[o];
        #pragma unroll
        for (int ct = 0; ct < 4; ct++) {
            int p = pbase + ct * 16 + lr;
            out[o * 2304 + p] = accs[ct][i] + b;
        }
    }
}

extern "C" void kernel_launch(void* const* d_in, const int* in_sizes, int n_in,
                              void* d_out, int out_size, void* d_ws, size_t ws_size,
                              hipStream_t stream) {
    const float* x  = (const float*)d_in[0];
    const float* Wq = (const float*)d_in[1];
    const float* bq = (const float*)d_in[2];
    const float* Wk = (const float*)d_in[3];
    const float* bk = (const float*)d_in[4];
    const float* Wv = (const float*)d_in[5];
    const float* bv = (const float*)d_in[6];
    const float* Wo = (const float*)d_in[7];
    const float* bo = (const float*)d_in[8];

    char* ws = (char*)d_ws;
    short* Wall = (short*)(ws);                     // 1024*256*2 = 524288 B
    short* xt   = (short*)(ws + 524288);            // 2304*256*2 = 1179648 B
    short* Qf   = (short*)(ws + 1703936);           // 9216*64*2
    short* Kf   = (short*)(ws + 2883584);           // 9216*64*2
    short* Vt   = (short*)(ws + 4063232);           // 64*9216*2
    short* Of   = (short*)(ws + 5242880);           // 2304*256*2
    float* pm   = (float*)(ws + 6422528);           // 4*576*16*4 = 147456
    float* ps   = (float*)(ws + 6569984);           // 147456
    float* pacc = (float*)(ws + 6717440);           // 4*576*1024*4 = 9437184 (end ~16.2MB)
    float* out  = (float*)d_out;

    k_cast_w<<<1024, 256, 0, stream>>>(Wq, Wk, Wv, Wo, Wall);
    k_transpose_x<<<dim3(36, 4), 256, 0, stream>>>(x, xt);
    k_gemm_qkv<<<dim3(12, 36), 256, 0, stream>>>(Wall, xt, bq, bk, bv, Qf, Kf, Vt);
    k_attn<<<dim3(576, 4), 512, 0, stream>>>(Qf, Kf, Vt, pm, ps, pacc);
    k_attn_combine<<<576, 256, 0, stream>>>(pm, ps, pacc, Of);
    k_gemm_out<<<dim3(4, 36), 256, 0, stream>>>(Wall + 768 * 256, Of, bo, out);
}

// Round 6
// 111.964 us; speedup vs baseline: 2.4535x; 2.4535x over previous
//
#include <hip/hip_runtime.h>
#include <stdint.h>

typedef __attribute__((ext_vector_type(4))) float f32x4;
typedef __attribute__((ext_vector_type(8))) short bf16x8;

#define MFMA(a, b, c) __builtin_amdgcn_mfma_f32_16x16x32_bf16(a, b, c, 0, 0, 0)

__device__ __forceinline__ short f2b(float f) {
    uint32_t u = __builtin_bit_cast(uint32_t, f);
    u += 0x7fffu + ((u >> 16) & 1u);
    return (short)(u >> 16);
}

typedef __attribute__((address_space(1))) const uint32_t gu32;
typedef __attribute__((address_space(3))) uint32_t su32;
__device__ __forceinline__ void stage16(const void* g, void* s) {
    // async global->LDS, 16B/lane; LDS dest = wave-uniform base + lane*16
    __builtin_amdgcn_global_load_lds((gu32*)g, (su32*)s, 16, 0, 0);
}

// ---------- cast [Wq;Wk;Wv;Wo] (fp32, each [256][256]) -> Wall bf16 [1024][256]
__global__ void k_cast_w(const float* __restrict__ Wq, const float* __restrict__ Wk,
                         const float* __restrict__ Wv, const float* __restrict__ Wo,
                         short* __restrict__ Wall) {
    int idx = blockIdx.x * 256 + threadIdx.x;   // grid = 1024 blocks
    int row = idx >> 8, col = idx & 255;
    float v;
    if (row < 256)      v = Wq[row * 256 + col];
    else if (row < 512) v = Wk[(row - 256) * 256 + col];
    else if (row < 768) v = Wv[(row - 512) * 256 + col];
    else                v = Wo[(row - 768) * 256 + col];
    Wall[idx] = f2b(v);
}

// ---------- transpose+cast x fp32 [256][2304] -> xt bf16 [2304][256]
__global__ void k_transpose_x(const float* __restrict__ x, short* __restrict__ xt) {
    __shared__ float tile[64][65];
    int pbase = blockIdx.x * 64, cbase = blockIdx.y * 64;  // grid (36,4)
    int tx = threadIdx.x & 63, tq = threadIdx.x >> 6;
    #pragma unroll
    for (int r = 0; r < 16; r++) {
        int row = tq * 16 + r;
        tile[row][tx] = x[(cbase + row) * 2304 + pbase + tx];
    }
    __syncthreads();
    #pragma unroll
    for (int r = 0; r < 16; r++) {
        int prow = tq * 16 + r;
        xt[(pbase + prow) * 256 + cbase + tx] = f2b(tile[tx][prow]);
    }
}

// ---------- QKV projection: C[768][2304] = Wall[0:768] @ x ; scatter to Qf/Kf/Vt
// Qf[n][64] bf16 (pre-scaled 1/8), Kf[n][64] bf16, Vt[64][9216] bf16, n = p*4+h
__global__ __launch_bounds__(256) void k_gemm_qkv(
    const short* __restrict__ Wall, const short* __restrict__ xt,
    const float* __restrict__ bq, const float* __restrict__ bk, const float* __restrict__ bv,
    short* __restrict__ Qf, short* __restrict__ Kf, short* __restrict__ Vt) {
    int t = threadIdx.x, wave = t >> 6, lane = t & 63, lr = lane & 15, lg = lane >> 4;
    int obase = blockIdx.x * 64 + wave * 16;   // grid.x = 12
    int pbase = blockIdx.y * 64;               // grid.y = 36
    const short* arow  = Wall + (obase + lr) * 256 + lg * 8;
    const short* brow0 = xt + (pbase +  0 + lr) * 256 + lg * 8;
    const short* brow1 = xt + (pbase + 16 + lr) * 256 + lg * 8;
    const short* brow2 = xt + (pbase + 32 + lr) * 256 + lg * 8;
    const short* brow3 = xt + (pbase + 48 + lr) * 256 + lg * 8;
    f32x4 acc0 = {0,0,0,0}, acc1 = {0,0,0,0}, acc2 = {0,0,0,0}, acc3 = {0,0,0,0};
    #pragma unroll
    for (int ks = 0; ks < 8; ks++) {
        bf16x8 a = *(const bf16x8*)(arow + ks * 32);
        acc0 = MFMA(a, *(const bf16x8*)(brow0 + ks * 32), acc0);
        acc1 = MFMA(a, *(const bf16x8*)(brow1 + ks * 32), acc1);
        acc2 = MFMA(a, *(const bf16x8*)(brow2 + ks * 32), acc2);
        acc3 = MFMA(a, *(const bf16x8*)(brow3 + ks * 32), acc3);
    }
    int w_idx = obase >> 8;  // 0=q 1=k 2=v, uniform per block
    const float* bias = (w_idx == 0) ? bq : (w_idx == 1) ? bk : bv;
    f32x4 accs[4] = {acc0, acc1, acc2, acc3};
    #pragma unroll
    for (int i = 0; i < 4; i++) {
        int o = obase + 4 * lg + i;
        int oo = o & 255;
        float b = bias[oo];
        int h = oo >> 6, d = oo & 63;
        #pragma unroll
        for (int ct = 0; ct < 4; ct++) {
            int p = pbase + ct * 16 + lr;
            float val = accs[ct][i] + b;
            int n = p * 4 + h;
            if (w_idx == 0)      Qf[n * 64 + d] = f2b(val * 0.125f);
            else if (w_idx == 1) Kf[n * 64 + d] = f2b(val);
            else                 Vt[d * 9216 + n] = f2b(val);
        }
    }
}

// ---------- flash attention: N=9216, d=64. Grid (72 qblocks, 4 kvblocks).
// Block = 8 waves x 512 thr = 128 queries (wave owns 16). Block iterates its
// 2304-key chunk in 36 tiles of 64 keys, K+V staged in LDS (global_load_lds,
// double-buffered, XOR-swizzled byte^=(row&7)<<4 via pre-swizzled global source
// per m173/m201). Waves consume tiles via ds_read_b128 (conflict-free).
// Fragment math identical to verified r4 mapping: swapped QK^T (mfma(K,Q)=S^T,
// permuted K rows) => S^T regs are the PV B-frag; ones-MFMA denominator;
// 3 parallel shfl_xor max-reduce. Per-wave partials (m, s, acc) -> ws.
__global__ __launch_bounds__(512) void k_attn(
    const short* __restrict__ Qf, const short* __restrict__ Kf,
    const short* __restrict__ Vt,
    float* __restrict__ pm, float* __restrict__ ps, float* __restrict__ pacc) {
    __shared__ short ktile[2][4096];   // [buf][64 keys][64 d] bf16, swizzled
    __shared__ short vtile[2][4096];   // [buf][64 dv][64 keys] bf16, swizzled
    int t = threadIdx.x, wave = t >> 6, lane = t & 63, lr = lane & 15, lg = lane >> 4;
    int kb = blockIdx.y;                       // grid.y = 4
    int qbase = blockIdx.x * 128 + wave * 16;  // grid.x = 72
    int kstart = kb * 2304;

    // Q fragments (16 queries per wave)
    const short* qrow = Qf + (qbase + lr) * 64 + lg * 8;
    bf16x8 q0 = *(const bf16x8*)(qrow);
    bf16x8 q1 = *(const bf16x8*)(qrow + 32);

    bf16x8 ones;
    #pragma unroll
    for (int i = 0; i < 8; i++) ones[i] = (short)0x3F80;   // bf16 1.0

    // ---- staging addresses: lane stages 16B of row (wave*8 + lane/8)
    int srow = wave * 8 + (lane >> 3);                    // tile-relative row 0..63
    int scol = ((lane & 7) ^ (lane >> 3)) << 4;           // pre-swizzled byte col
    const char* ksrc = (const char*)Kf + (size_t)(kstart + srow) * 128 + scol; // +8192/tile
    const char* vsrc = (const char*)Vt + (size_t)srow * 18432 + kstart * 2 + scol; // +128/tile
    short* kdst[2] = { &ktile[0][wave * 512], &ktile[1][wave * 512] };
    short* vdst[2] = { &vtile[0][wave * 512], &vtile[1][wave * 512] };

    // ---- ds_read byte offsets (tile-relative, swizzle applied on read side)
    int perm = (lr & 3) + 8 * (lr >> 2);   // K-row permutation: st regs -> B-frag layout
    int cw = lg * 16;
    int sw0 = (perm & 7) << 4, sw1 = ((perm + 4) & 7) << 4, swv = (lr & 7) << 4;
    int kOff00 = perm * 128 + (cw ^ sw0);
    int kOff01 = perm * 128 + ((cw + 64) ^ sw0);
    int kOff10 = (perm + 4) * 128 + (cw ^ sw1);
    int kOff11 = (perm + 4) * 128 + ((cw + 64) ^ sw1);
    int vOff0 = (lr +  0) * 128 + (cw ^ swv);
    int vOff1 = (lr + 16) * 128 + (cw ^ swv);
    int vOff2 = (lr + 32) * 128 + (cw ^ swv);
    int vOff3 = (lr + 48) * 128 + (cw ^ swv);

    float mA = -1e30f;
    f32x4 zv = {0,0,0,0};
    f32x4 acc0 = zv, acc1 = zv, acc2 = zv, acc3 = zv, sacc = zv;

    // prologue: stage tile 0 into buf 0
    stage16(ksrc, kdst[0]);
    stage16(vsrc, vdst[0]);

    for (int tt = 0; tt < 36; tt++) {
        __syncthreads();                 // drains own vmcnt -> tile tt staged, all waves
        int buf = tt & 1;
        if (tt + 1 < 36) {               // stage next tile into other buffer
            stage16(ksrc + (size_t)(tt + 1) * 8192, kdst[buf ^ 1]);
            stage16(vsrc + (size_t)(tt + 1) * 128,  vdst[buf ^ 1]);
        }
        const char* kt = (const char*)&ktile[buf][0];
        const char* vt = (const char*)&vtile[buf][0];
        #pragma unroll
        for (int s = 0; s < 2; s++) {
            int sk = s * 4096;           // K sub-step moves rows (+32 keys)
            int sx = s * 64;             // V sub-step moves cols (XOR bit 6)
            bf16x8 k00 = *(const bf16x8*)(kt + sk + kOff00);
            bf16x8 k01 = *(const bf16x8*)(kt + sk + kOff01);
            bf16x8 k10 = *(const bf16x8*)(kt + sk + kOff10);
            bf16x8 k11 = *(const bf16x8*)(kt + sk + kOff11);

            // QK^T (S^T): rows = keys (perm'd), cols = queries
            f32x4 st0 = MFMA(k00, q0, zv); st0 = MFMA(k01, q1, st0);
            f32x4 st1 = MFMA(k10, q0, zv); st1 = MFMA(k11, q1, st1);

            // online softmax over these 32 keys for q = qbase+lr
            float tm = fmaxf(fmaxf(fmaxf(st0[0], st0[1]), fmaxf(st0[2], st0[3])),
                             fmaxf(fmaxf(st1[0], st1[1]), fmaxf(st1[2], st1[3])));
            float ta = __shfl_xor(tm, 16);
            float tb = __shfl_xor(tm, 32);
            float tc = __shfl_xor(tm, 48);
            tm = fmaxf(fmaxf(tm, ta), fmaxf(tb, tc));
            float mn = fmaxf(mA, tm);
            float sc = __expf(mA - mn);
            mA = mn;
            bf16x8 pb;
            pb[0] = f2b(__expf(st0[0] - mn)); pb[1] = f2b(__expf(st0[1] - mn));
            pb[2] = f2b(__expf(st0[2] - mn)); pb[3] = f2b(__expf(st0[3] - mn));
            pb[4] = f2b(__expf(st1[0] - mn)); pb[5] = f2b(__expf(st1[1] - mn));
            pb[6] = f2b(__expf(st1[2] - mn)); pb[7] = f2b(__expf(st1[3] - mn));

            bf16x8 v0 = *(const bf16x8*)(vt + (vOff0 ^ sx));
            bf16x8 v1 = *(const bf16x8*)(vt + (vOff1 ^ sx));
            bf16x8 v2 = *(const bf16x8*)(vt + (vOff2 ^ sx));
            bf16x8 v3 = *(const bf16x8*)(vt + (vOff3 ^ sx));

            // PV + denominator (ones-MFMA); rescale accumulators by sc
            acc0 = MFMA(v0, pb, acc0 * sc);
            acc1 = MFMA(v1, pb, acc1 * sc);
            acc2 = MFMA(v2, pb, acc2 * sc);
            acc3 = MFMA(v3, pb, acc3 * sc);
            sacc = MFMA(ones, pb, sacc * sc);
        }
    }

    // ---- per-wave partial out: pacc[pidx][q=lr][dv], pm/ps[pidx][q]
    int n16 = blockIdx.x * 8 + wave;     // 0..575 global 16-query group
    int pidx = kb * 576 + n16;
    float* pa = pacc + (size_t)pidx * 1024 + lr * 64 + lg * 4;
    *(f32x4*)(pa +  0) = acc0;
    *(f32x4*)(pa + 16) = acc1;
    *(f32x4*)(pa + 32) = acc2;
    *(f32x4*)(pa + 48) = acc3;
    if (lg == 0) {                       // sacc[0] = s[q=lr] (all C-rows equal)
        pm[pidx * 16 + lr] = mA;
        ps[pidx * 16 + lr] = sacc[0];
    }
}

// ---------- combine 4 KV-split partials -> Of bf16 [2304][256]
__global__ __launch_bounds__(256) void k_attn_combine(
    const float* __restrict__ pm, const float* __restrict__ ps,
    const float* __restrict__ pacc, short* __restrict__ Of) {
    int qb = blockIdx.x, t = threadIdx.x;   // grid = 576
    #pragma unroll
    for (int r = 0; r < 4; r++) {
        int idx = t + 256 * r;              // 0..1023 : [q][dv]
        int q = idx >> 6, dv = idx & 63;
        float m0 = pm[(0 * 576 + qb) * 16 + q], m1 = pm[(1 * 576 + qb) * 16 + q];
        float m2 = pm[(2 * 576 + qb) * 16 + q], m3 = pm[(3 * 576 + qb) * 16 + q];
        float mg = fmaxf(fmaxf(m0, m1), fmaxf(m2, m3));
        float e0 = __expf(m0 - mg), e1 = __expf(m1 - mg);
        float e2 = __expf(m2 - mg), e3 = __expf(m3 - mg);
        float S = ps[(0 * 576 + qb) * 16 + q] * e0 + ps[(1 * 576 + qb) * 16 + q] * e1
                + ps[(2 * 576 + qb) * 16 + q] * e2 + ps[(3 * 576 + qb) * 16 + q] * e3;
        float O = pacc[(size_t)(0 * 576 + qb) * 1024 + idx] * e0
                + pacc[(size_t)(1 * 576 + qb) * 1024 + idx] * e1
                + pacc[(size_t)(2 * 576 + qb) * 1024 + idx] * e2
                + pacc[(size_t)(3 * 576 + qb) * 1024 + idx] * e3;
        int n = qb * 16 + q, p = n >> 2, hh = n & 3;
        Of[p * 256 + hh * 64 + dv] = f2b(O / S);
    }
}

// ---------- output projection: out[256][2304] = Wo @ Of^T + bo (fp32 out, NCHW)
__global__ __launch_bounds__(256) void k_gemm_out(
    const short* __restrict__ Wo_bf, const short* __restrict__ Of,
    const float* __restrict__ bo, float* __restrict__ out) {
    int t = threadIdx.x, wave = t >> 6, lane = t & 63, lr = lane & 15, lg = lane >> 4;
    int obase = blockIdx.x * 64 + wave * 16;   // grid.x = 4
    int pbase = blockIdx.y * 64;               // grid.y = 36
    const short* arow  = Wo_bf + (obase + lr) * 256 + lg * 8;
    const short* brow0 = Of + (pbase +  0 + lr) * 256 + lg * 8;
    const short* brow1 = Of + (pbase + 16 + lr) * 256 + lg * 8;
    const short* brow2 = Of + (pbase + 32 + lr) * 256 + lg * 8;
    const short* brow3 = Of + (pbase + 48 + lr) * 256 + lg * 8;
    f32x4 acc0 = {0,0,0,0}, acc1 = {0,0,0,0}, acc2 = {0,0,0,0}, acc3 = {0,0,0,0};
    #pragma unroll
    for (int ks = 0; ks < 8; ks++) {
        bf16x8 a = *(const bf16x8*)(arow + ks * 32);
        acc0 = MFMA(a, *(const bf16x8*)(brow0 + ks * 32), acc0);
        acc1 = MFMA(a, *(const bf16x8*)(brow1 + ks * 32), acc1);
        acc2 = MFMA(a, *(const bf16x8*)(brow2 + ks * 32), acc2);
        acc3 = MFMA(a, *(const bf16x8*)(brow3 + ks * 32), acc3);
    }
    f32x4 accs[4] = {acc0, acc1, acc2, acc3};
    #pragma unroll
    for (int i = 0; i < 4; i++) {
        int o = obase + 4 * lg + i;
        float b = bo[o];
        #pragma unroll
        for (int ct = 0; ct < 4; ct++) {
            int p = pbase + ct * 16 + lr;
            out[o * 2304 + p] = accs[ct][i] + b;
        }
    }
}

extern "C" void kernel_launch(void* const* d_in, const int* in_sizes, int n_in,
                              void* d_out, int out_size, void* d_ws, size_t ws_size,
                              hipStream_t stream) {
    const float* x  = (const float*)d_in[0];
    const float* Wq = (const float*)d_in[1];
    const float* bq = (const float*)d_in[2];
    const float* Wk = (const float*)d_in[3];
    const float* bk = (const float*)d_in[4];
    const float* Wv = (const float*)d_in[5];
    const float* bv = (const float*)d_in[6];
    const float* Wo = (const float*)d_in[7];
    const float* bo = (const float*)d_in[8];

    char* ws = (char*)d_ws;
    short* Wall = (short*)(ws);                     // 1024*256*2 = 524288 B
    short* xt   = (short*)(ws + 524288);            // 2304*256*2 = 1179648 B
    short* Qf   = (short*)(ws + 1703936);           // 9216*64*2
    short* Kf   = (short*)(ws + 2883584);           // 9216*64*2
    short* Vt   = (short*)(ws + 4063232);           // 64*9216*2
    short* Of   = (short*)(ws + 5242880);           // 2304*256*2
    float* pm   = (float*)(ws + 6422528);           // 4*576*16*4 = 147456
    float* ps   = (float*)(ws + 6569984);           // 147456
    float* pacc = (float*)(ws + 6717440);           // 4*576*1024*4 = 9437184 (end ~16.2MB)
    float* out  = (float*)d_out;

    k_cast_w<<<1024, 256, 0, stream>>>(Wq, Wk, Wv, Wo, Wall);
    k_transpose_x<<<dim3(36, 4), 256, 0, stream>>>(x, xt);
    k_gemm_qkv<<<dim3(12, 36), 256, 0, stream>>>(Wall, xt, bq, bk, bv, Qf, Kf, Vt);
    k_attn<<<dim3(72, 4), 512, 0, stream>>>(Qf, Kf, Vt, pm, ps, pacc);
    k_attn_combine<<<576, 256, 0, stream>>>(pm, ps, pacc, Of);
    k_gemm_out<<<dim3(4, 36), 256, 0, stream>>>(Wall + 768 * 256, Of, bo, out);
}

// Round 7
// 94.342 us; speedup vs baseline: 2.9117x; 1.1868x over previous
//
#include <hip/hip_runtime.h>
#include <stdint.h>

typedef __attribute__((ext_vector_type(4))) float f32x4;
typedef __attribute__((ext_vector_type(8))) short bf16x8;

#define MFMA(a, b, c) __builtin_amdgcn_mfma_f32_16x16x32_bf16(a, b, c, 0, 0, 0)

__device__ __forceinline__ short f2b(float f) {
    uint32_t u = __builtin_bit_cast(uint32_t, f);
    u += 0x7fffu + ((u >> 16) & 1u);
    return (short)(u >> 16);
}

__device__ __forceinline__ float ex2(float x) {   // raw v_exp_f32: 2^x
    float r; asm("v_exp_f32 %0, %1" : "=v"(r) : "v"(x)); return r;
}
__device__ __forceinline__ uint32_t cvtpk(float lo, float hi) {  // 2xf32 -> packed bf16
    uint32_t r; asm("v_cvt_pk_bf16_f32 %0, %1, %2" : "=v"(r) : "v"(lo), "v"(hi)); return r;
}

typedef __attribute__((address_space(1))) const uint32_t gu32;
typedef __attribute__((address_space(3))) uint32_t su32;
__device__ __forceinline__ void stage16(const void* g, void* s) {
    // async global->LDS, 16B/lane; LDS dest = wave-uniform base + lane*16
    __builtin_amdgcn_global_load_lds((gu32*)g, (su32*)s, 16, 0, 0);
}

// bank-conflict-free slot swizzle for our row sets (K rows: perm-residues; V rows: lr+16k)
__device__ __forceinline__ int FSW(int r) { return (r & 3) | (((r >> 3) & 1) << 2); }

// Qf pre-scale: (1/sqrt(64)) * log2(e)  -> scores in log2 domain, P = 2^(S-m)
#define QSCALE 0.1803368801111601f

// ---------- cast [Wq;Wk;Wv;Wo] (fp32, each [256][256]) -> Wall bf16 [1024][256]
__global__ void k_cast_w(const float* __restrict__ Wq, const float* __restrict__ Wk,
                         const float* __restrict__ Wv, const float* __restrict__ Wo,
                         short* __restrict__ Wall) {
    int idx = blockIdx.x * 256 + threadIdx.x;   // grid = 1024 blocks
    int row = idx >> 8, col = idx & 255;
    float v;
    if (row < 256)      v = Wq[row * 256 + col];
    else if (row < 512) v = Wk[(row - 256) * 256 + col];
    else if (row < 768) v = Wv[(row - 512) * 256 + col];
    else                v = Wo[(row - 768) * 256 + col];
    Wall[idx] = f2b(v);
}

// ---------- transpose+cast x fp32 [256][2304] -> xt bf16 [2304][256]
__global__ void k_transpose_x(const float* __restrict__ x, short* __restrict__ xt) {
    __shared__ float tile[64][65];
    int pbase = blockIdx.x * 64, cbase = blockIdx.y * 64;  // grid (36,4)
    int tx = threadIdx.x & 63, tq = threadIdx.x >> 6;
    #pragma unroll
    for (int r = 0; r < 16; r++) {
        int row = tq * 16 + r;
        tile[row][tx] = x[(cbase + row) * 2304 + pbase + tx];
    }
    __syncthreads();
    #pragma unroll
    for (int r = 0; r < 16; r++) {
        int prow = tq * 16 + r;
        xt[(pbase + prow) * 256 + cbase + tx] = f2b(tile[tx][prow]);
    }
}

// ---------- QKV projection: C[768][2304] = Wall[0:768] @ x ; scatter to Qf/Kf/Vt
// Qf[n][64] bf16 (pre-scaled QSCALE), Kf[n][64] bf16, Vt[64][9216] bf16, n = p*4+h
__global__ __launch_bounds__(256) void k_gemm_qkv(
    const short* __restrict__ Wall, const short* __restrict__ xt,
    const float* __restrict__ bq, const float* __restrict__ bk, const float* __restrict__ bv,
    short* __restrict__ Qf, short* __restrict__ Kf, short* __restrict__ Vt) {
    int t = threadIdx.x, wave = t >> 6, lane = t & 63, lr = lane & 15, lg = lane >> 4;
    int obase = blockIdx.x * 64 + wave * 16;   // grid.x = 12
    int pbase = blockIdx.y * 64;               // grid.y = 36
    const short* arow  = Wall + (obase + lr) * 256 + lg * 8;
    const short* brow0 = xt + (pbase +  0 + lr) * 256 + lg * 8;
    const short* brow1 = xt + (pbase + 16 + lr) * 256 + lg * 8;
    const short* brow2 = xt + (pbase + 32 + lr) * 256 + lg * 8;
    const short* brow3 = xt + (pbase + 48 + lr) * 256 + lg * 8;
    f32x4 acc0 = {0,0,0,0}, acc1 = {0,0,0,0}, acc2 = {0,0,0,0}, acc3 = {0,0,0,0};
    #pragma unroll
    for (int ks = 0; ks < 8; ks++) {
        bf16x8 a = *(const bf16x8*)(arow + ks * 32);
        acc0 = MFMA(a, *(const bf16x8*)(brow0 + ks * 32), acc0);
        acc1 = MFMA(a, *(const bf16x8*)(brow1 + ks * 32), acc1);
        acc2 = MFMA(a, *(const bf16x8*)(brow2 + ks * 32), acc2);
        acc3 = MFMA(a, *(const bf16x8*)(brow3 + ks * 32), acc3);
    }
    int w_idx = obase >> 8;  // 0=q 1=k 2=v, uniform per block
    const float* bias = (w_idx == 0) ? bq : (w_idx == 1) ? bk : bv;
    f32x4 accs[4] = {acc0, acc1, acc2, acc3};
    #pragma unroll
    for (int i = 0; i < 4; i++) {
        int o = obase + 4 * lg + i;
        int oo = o & 255;
        float b = bias[oo];
        int h = oo >> 6, d = oo & 63;
        #pragma unroll
        for (int ct = 0; ct < 4; ct++) {
            int p = pbase + ct * 16 + lr;
            float val = accs[ct][i] + b;
            int n = p * 4 + h;
            if (w_idx == 0)      Qf[n * 64 + d] = f2b(val * QSCALE);
            else if (w_idx == 1) Kf[n * 64 + d] = f2b(val);
            else                 Vt[d * 9216 + n] = f2b(val);
        }
    }
}

// ---------- flash attention: N=9216, d=64. Grid (144 qblocks, nsplit kvchunks).
// Block = 4 waves x 256 thr = 64 queries (wave owns 16). Block walks its key
// chunk in tiles of 64 keys; K [64][64] + V [64dv][64k] staged via
// global_load_lds (double-buffered), slot-swizzled with FSW (conflict-free for
// both the K-read row set {perm residues} and the V-read row set {lr+16k}).
// Merged 64-key softmax in log2 domain (Qf pre-scaled by log2e/8; raw v_exp);
// defer-max THR=11 (log2) skips rescale on most tiles; cvt_pk packs P to bf16.
// Swapped QK^T (mfma(K,Q)=S^T, perm'd rows) => st regs are the PV B-frag.
__global__ __launch_bounds__(256) void k_attn(
    const short* __restrict__ Qf, const short* __restrict__ Kf,
    const short* __restrict__ Vt, int keysPer, int ntiles,
    float* __restrict__ pm, float* __restrict__ ps, float* __restrict__ pacc) {
    __shared__ short ktile[2][4096];   // [buf][64 keys][64 d], slot-swizzled
    __shared__ short vtile[2][4096];   // [buf][64 dv][64 keys], slot-swizzled
    int t = threadIdx.x, wave = t >> 6, lane = t & 63, lr = lane & 15, lg = lane >> 4;
    int kb = blockIdx.y;
    int qbase = blockIdx.x * 64 + wave * 16;   // grid.x = 144
    int kstart = kb * keysPer;

    const short* qrow = Qf + (qbase + lr) * 64 + lg * 8;
    bf16x8 q0 = *(const bf16x8*)(qrow);
    bf16x8 q1 = *(const bf16x8*)(qrow + 32);

    bf16x8 ones;
    #pragma unroll
    for (int i = 0; i < 8; i++) ones[i] = (short)0x3F80;   // bf16 1.0

    // ---- staging: wave stages 16 rows (2 calls x 8 rows); lane -> 16B slot
    int sr = lane >> 3;                       // 0..7 row-within-call
    int srow0 = wave * 16 + sr, srow1 = srow0 + 8;
    int slot = lane & 7;
    int col0 = (slot ^ FSW(srow0)) << 4;      // pre-swizzled global byte col
    int col1 = (slot ^ FSW(srow1)) << 4;
    const char* kS0 = (const char*)Kf + (size_t)(kstart + srow0) * 128 + col0;
    const char* kS1 = (const char*)Kf + (size_t)(kstart + srow1) * 128 + col1;
    const char* vS0 = (const char*)Vt + (size_t)srow0 * 18432 + (size_t)kstart * 2 + col0;
    const char* vS1 = (const char*)Vt + (size_t)srow1 * 18432 + (size_t)kstart * 2 + col1;
    short* kD0[2] = { &ktile[0][wave * 1024], &ktile[1][wave * 1024] };
    short* kD1[2] = { kD0[0] + 512, kD0[1] + 512 };
    short* vD0[2] = { &vtile[0][wave * 1024], &vtile[1][wave * 1024] };
    short* vD1[2] = { vD0[0] + 512, vD0[1] + 512 };

    // ---- ds_read byte offsets (tile-relative; FSW applied on read side)
    int perm = (lr & 3) + 8 * (lr >> 2);   // K-row perm: st regs -> keys 8*lg+i
    int cb = lg * 16;
    int kOffA0 = perm * 128       + (cb        ^ (FSW(perm) << 4));
    int kOffA1 = perm * 128       + ((cb + 64) ^ (FSW(perm) << 4));
    int kOffB0 = (perm + 4) * 128 + (cb        ^ (FSW(perm + 4) << 4));
    int kOffB1 = (perm + 4) * 128 + ((cb + 64) ^ (FSW(perm + 4) << 4));
    int vOff   = lr * 128         + (cb        ^ (FSW(lr) << 4));
    // V rows lr+16k share FSW(lr); +16 rows = +2048B. 2nd key-half = ^64.

    float mA = -1e30f;
    f32x4 zv = {0,0,0,0};
    f32x4 acc0 = zv, acc1 = zv, acc2 = zv, acc3 = zv, sacc = zv;

    // prologue: stage tile 0 into buf 0
    stage16(kS0, kD0[0]); stage16(kS1, kD1[0]);
    stage16(vS0, vD0[0]); stage16(vS1, vD1[0]);

    for (int tt = 0; tt < ntiles; tt++) {
        __syncthreads();                 // drain -> tile tt staged for all waves
        int buf = tt & 1;
        if (tt + 1 < ntiles) {
            size_t ko = (size_t)(tt + 1) * 8192, vo = (size_t)(tt + 1) * 128;
            stage16(kS0 + ko, kD0[buf ^ 1]); stage16(kS1 + ko, kD1[buf ^ 1]);
            stage16(vS0 + vo, vD0[buf ^ 1]); stage16(vS1 + vo, vD1[buf ^ 1]);
        }
        const char* kt = (const char*)&ktile[buf][0];
        const char* vt = (const char*)&vtile[buf][0];

        // QK^T for all 64 keys (S^T): keys 0..31 -> st0,st1; 32..63 -> st2,st3
        bf16x8 kA0 = *(const bf16x8*)(kt + kOffA0);
        bf16x8 kA1 = *(const bf16x8*)(kt + kOffA1);
        bf16x8 kB0 = *(const bf16x8*)(kt + kOffB0);
        bf16x8 kB1 = *(const bf16x8*)(kt + kOffB1);
        f32x4 st0 = MFMA(kA0, q0, zv); st0 = MFMA(kA1, q1, st0);
        f32x4 st1 = MFMA(kB0, q0, zv); st1 = MFMA(kB1, q1, st1);
        bf16x8 kC0 = *(const bf16x8*)(kt + 4096 + kOffA0);
        bf16x8 kC1 = *(const bf16x8*)(kt + 4096 + kOffA1);
        bf16x8 kD_ = *(const bf16x8*)(kt + 4096 + kOffB0);
        bf16x8 kD1_ = *(const bf16x8*)(kt + 4096 + kOffB1);
        f32x4 st2 = MFMA(kC0, q0, zv); st2 = MFMA(kC1, q1, st2);
        f32x4 st3 = MFMA(kD_, q0, zv); st3 = MFMA(kD1_, q1, st3);

        // ---- merged softmax over 64 keys (log2 domain)
        float tm = fmaxf(
            fmaxf(fmaxf(fmaxf(st0[0], st0[1]), fmaxf(st0[2], st0[3])),
                  fmaxf(fmaxf(st1[0], st1[1]), fmaxf(st1[2], st1[3]))),
            fmaxf(fmaxf(fmaxf(st2[0], st2[1]), fmaxf(st2[2], st2[3])),
                  fmaxf(fmaxf(st3[0], st3[1]), fmaxf(st3[2], st3[3]))));
        float ta = __shfl_xor(tm, 16);
        float tb = __shfl_xor(tm, 32);
        float tc = __shfl_xor(tm, 48);
        tm = fmaxf(fmaxf(tm, ta), fmaxf(tb, tc));
        if (!__all(tm - mA <= 11.0f)) {        // defer-max: rescale rarely
            float mn = fmaxf(mA, tm);
            float sc = ex2(mA - mn);
            acc0 *= sc; acc1 *= sc; acc2 *= sc; acc3 *= sc; sacc *= sc;
            mA = mn;
        }
        union { uint32_t w[4]; bf16x8 v; } pa, pb;
        pa.w[0] = cvtpk(ex2(st0[0] - mA), ex2(st0[1] - mA));
        pa.w[1] = cvtpk(ex2(st0[2] - mA), ex2(st0[3] - mA));
        pa.w[2] = cvtpk(ex2(st1[0] - mA), ex2(st1[1] - mA));
        pa.w[3] = cvtpk(ex2(st1[2] - mA), ex2(st1[3] - mA));
        pb.w[0] = cvtpk(ex2(st2[0] - mA), ex2(st2[1] - mA));
        pb.w[1] = cvtpk(ex2(st2[2] - mA), ex2(st2[3] - mA));
        pb.w[2] = cvtpk(ex2(st3[0] - mA), ex2(st3[1] - mA));
        pb.w[3] = cvtpk(ex2(st3[2] - mA), ex2(st3[3] - mA));

        // ---- PV over both key halves + denominator
        bf16x8 v0a = *(const bf16x8*)(vt + vOff);
        bf16x8 v0b = *(const bf16x8*)(vt + (vOff ^ 64));
        bf16x8 v1a = *(const bf16x8*)(vt + vOff + 2048);
        bf16x8 v1b = *(const bf16x8*)(vt + ((vOff + 2048) ^ 64));
        bf16x8 v2a = *(const bf16x8*)(vt + vOff + 4096);
        bf16x8 v2b = *(const bf16x8*)(vt + ((vOff + 4096) ^ 64));
        bf16x8 v3a = *(const bf16x8*)(vt + vOff + 6144);
        bf16x8 v3b = *(const bf16x8*)(vt + ((vOff + 6144) ^ 64));
        acc0 = MFMA(v0a, pa.v, acc0); acc0 = MFMA(v0b, pb.v, acc0);
        acc1 = MFMA(v1a, pa.v, acc1); acc1 = MFMA(v1b, pb.v, acc1);
        acc2 = MFMA(v2a, pa.v, acc2); acc2 = MFMA(v2b, pb.v, acc2);
        acc3 = MFMA(v3a, pa.v, acc3); acc3 = MFMA(v3b, pb.v, acc3);
        sacc = MFMA(ones, pa.v, sacc); sacc = MFMA(ones, pb.v, sacc);
    }

    // ---- per-wave partial out
    int g = blockIdx.x * 4 + wave;       // 0..575 global 16-query group
    int pidx = kb * 576 + g;
    float* pa_ = pacc + (size_t)pidx * 1024 + lr * 64 + lg * 4;
    *(f32x4*)(pa_ +  0) = acc0;
    *(f32x4*)(pa_ + 16) = acc1;
    *(f32x4*)(pa_ + 32) = acc2;
    *(f32x4*)(pa_ + 48) = acc3;
    if (lg == 0) {                       // sacc[0] = s[q=lr]
        pm[pidx * 16 + lr] = mA;
        ps[pidx * 16 + lr] = sacc[0];
    }
}

// ---------- combine nsplit KV-chunk partials -> Of bf16 [2304][256]
__global__ __launch_bounds__(256) void k_attn_combine(
    const float* __restrict__ pm, const float* __restrict__ ps,
    const float* __restrict__ pacc, short* __restrict__ Of, int nsplit) {
    int qb = blockIdx.x, t = threadIdx.x;   // grid = 576
    #pragma unroll
    for (int r = 0; r < 4; r++) {
        int idx = t + 256 * r;              // 0..1023 : [q][dv]
        int q = idx >> 6, dv = idx & 63;
        float mg = -1e30f;
        for (int s = 0; s < nsplit; s++)
            mg = fmaxf(mg, pm[(s * 576 + qb) * 16 + q]);
        float S = 0.f, O = 0.f;
        for (int s = 0; s < nsplit; s++) {
            float e = ex2(pm[(s * 576 + qb) * 16 + q] - mg);   // log2 domain
            S += ps[(s * 576 + qb) * 16 + q] * e;
            O += pacc[(size_t)(s * 576 + qb) * 1024 + idx] * e;
        }
        int n = qb * 16 + q, p = n >> 2, hh = n & 3;
        Of[p * 256 + hh * 64 + dv] = f2b(O / S);
    }
}

// ---------- output projection: out[256][2304] = Wo @ Of^T + bo (fp32 out, NCHW)
__global__ __launch_bounds__(256) void k_gemm_out(
    const short* __restrict__ Wo_bf, const short* __restrict__ Of,
    const float* __restrict__ bo, float* __restrict__ out) {
    int t = threadIdx.x, wave = t >> 6, lane = t & 63, lr = lane & 15, lg = lane >> 4;
    int obase = blockIdx.x * 64 + wave * 16;   // grid.x = 4
    int pbase = blockIdx.y * 64;               // grid.y = 36
    const short* arow  = Wo_bf + (obase + lr) * 256 + lg * 8;
    const short* brow0 = Of + (pbase +  0 + lr) * 256 + lg * 8;
    const short* brow1 = Of + (pbase + 16 + lr) * 256 + lg * 8;
    const short* brow2 = Of + (pbase + 32 + lr) * 256 + lg * 8;
    const short* brow3 = Of + (pbase + 48 + lr) * 256 + lg * 8;
    f32x4 acc0 = {0,0,0,0}, acc1 = {0,0,0,0}, acc2 = {0,0,0,0}, acc3 = {0,0,0,0};
    #pragma unroll
    for (int ks = 0; ks < 8; ks++) {
        bf16x8 a = *(const bf16x8*)(arow + ks * 32);
        acc0 = MFMA(a, *(const bf16x8*)(brow0 + ks * 32), acc0);
        acc1 = MFMA(a, *(const bf16x8*)(brow1 + ks * 32), acc1);
        acc2 = MFMA(a, *(const bf16x8*)(brow2 + ks * 32), acc2);
        acc3 = MFMA(a, *(const bf16x8*)(brow3 + ks * 32), acc3);
    }
    f32x4 accs[4] = {acc0, acc1, acc2, acc3};
    #pragma unroll
    for (int i = 0; i < 4; i++) {
        int o = obase + 4 * lg + i;
        float b = bo[o];
        #pragma unroll
        for (int ct = 0; ct < 4; ct++) {
            int p = pbase + ct * 16 + lr;
            out[o * 2304 + p] = accs[ct][i] + b;
        }
    }
}

extern "C" void kernel_launch(void* const* d_in, const int* in_sizes, int n_in,
                              void* d_out, int out_size, void* d_ws, size_t ws_size,
                              hipStream_t stream) {
    const float* x  = (const float*)d_in[0];
    const float* Wq = (const float*)d_in[1];
    const float* bq = (const float*)d_in[2];
    const float* Wk = (const float*)d_in[3];
    const float* bk = (const float*)d_in[4];
    const float* Wv = (const float*)d_in[5];
    const float* bv = (const float*)d_in[6];
    const float* Wo = (const float*)d_in[7];
    const float* bo = (const float*)d_in[8];

    char* ws = (char*)d_ws;
    short* Wall = (short*)(ws);                     // 1024*256*2 = 524288 B
    short* xt   = (short*)(ws + 524288);            // 2304*256*2
    short* Qf   = (short*)(ws + 1703936);           // 9216*64*2
    short* Kf   = (short*)(ws + 2883584);           // 9216*64*2
    short* Vt   = (short*)(ws + 4063232);           // 64*9216*2
    short* Of   = (short*)(ws + 5242880);           // 2304*256*2 (ends 6422528)
    float* pm   = (float*)(ws + 6422528);           // 8*576*16*4 = 294912 max
    float* ps   = (float*)(ws + 6717440);           // 294912 max
    float* pacc = (float*)(ws + 7012352);           // nsplit*576*1024*4
    float* out  = (float*)d_out;

    // nsplit=8 needs ws end ~25.9MB; fall back to 4 (16.4MB) if ws is small
    int nsplit = (ws_size >= (size_t)7012352 + 8u * 2359296u) ? 8 : 4;
    int keysPer = 9216 / nsplit;
    int ntiles = keysPer / 64;

    k_cast_w<<<1024, 256, 0, stream>>>(Wq, Wk, Wv, Wo, Wall);
    k_transpose_x<<<dim3(36, 4), 256, 0, stream>>>(x, xt);
    k_gemm_qkv<<<dim3(12, 36), 256, 0, stream>>>(Wall, xt, bq, bk, bv, Qf, Kf, Vt);
    k_attn<<<dim3(144, nsplit), 256, 0, stream>>>(Qf, Kf, Vt, keysPer, ntiles, pm, ps, pacc);
    k_attn_combine<<<576, 256, 0, stream>>>(pm, ps, pacc, Of, nsplit);
    k_gemm_out<<<dim3(4, 36), 256, 0, stream>>>(Wall + 768 * 256, Of, bo, out);
}

// Round 8
// 91.256 us; speedup vs baseline: 3.0102x; 1.0338x over previous
//
#include <hip/hip_runtime.h>
#include <stdint.h>

typedef __attribute__((ext_vector_type(4))) float f32x4;
typedef __attribute__((ext_vector_type(8))) short bf16x8;

#define MFMA(a, b, c) __builtin_amdgcn_mfma_f32_16x16x32_bf16(a, b, c, 0, 0, 0)

__device__ __forceinline__ short f2b(float f) {
    uint32_t u = __builtin_bit_cast(uint32_t, f);
    u += 0x7fffu + ((u >> 16) & 1u);
    return (short)(u >> 16);
}

__device__ __forceinline__ float ex2(float x) {   // raw v_exp_f32: 2^x
    float r; asm("v_exp_f32 %0, %1" : "=v"(r) : "v"(x)); return r;
}
__device__ __forceinline__ uint32_t cvtpk(float lo, float hi) {  // 2xf32 -> packed bf16
    uint32_t r; asm("v_cvt_pk_bf16_f32 %0, %1, %2" : "=v"(r) : "v"(lo), "v"(hi)); return r;
}

typedef __attribute__((address_space(1))) const uint32_t gu32;
typedef __attribute__((address_space(3))) uint32_t su32;
__device__ __forceinline__ void stage16(const void* g, void* s) {
    // async global->LDS, 16B/lane; LDS dest = wave-uniform base + lane*16
    __builtin_amdgcn_global_load_lds((gu32*)g, (su32*)s, 16, 0, 0);
}

// bank-conflict-free slot swizzle (verified 0 conflicts in r7)
__device__ __forceinline__ int FSW(int r) { return (r & 3) | (((r >> 3) & 1) << 2); }

// Qf pre-scale: (1/sqrt(64)) * log2(e)  -> scores in log2 domain, P = 2^(S-m)
#define QSCALE 0.1803368801111601f

// ---------- cast [Wq;Wk;Wv;Wo] (fp32, each [256][256]) -> Wall bf16 [1024][256]
__global__ void k_cast_w(const float* __restrict__ Wq, const float* __restrict__ Wk,
                         const float* __restrict__ Wv, const float* __restrict__ Wo,
                         short* __restrict__ Wall) {
    int idx = blockIdx.x * 256 + threadIdx.x;   // grid = 1024 blocks
    int row = idx >> 8, col = idx & 255;
    float v;
    if (row < 256)      v = Wq[row * 256 + col];
    else if (row < 512) v = Wk[(row - 256) * 256 + col];
    else if (row < 768) v = Wv[(row - 512) * 256 + col];
    else                v = Wo[(row - 768) * 256 + col];
    Wall[idx] = f2b(v);
}

// ---------- transpose+cast x fp32 [256][2304] -> xt bf16 [2304][256]
__global__ void k_transpose_x(const float* __restrict__ x, short* __restrict__ xt) {
    __shared__ float tile[64][65];
    int pbase = blockIdx.x * 64, cbase = blockIdx.y * 64;  // grid (36,4)
    int tx = threadIdx.x & 63, tq = threadIdx.x >> 6;
    #pragma unroll
    for (int r = 0; r < 16; r++) {
        int row = tq * 16 + r;
        tile[row][tx] = x[(cbase + row) * 2304 + pbase + tx];
    }
    __syncthreads();
    #pragma unroll
    for (int r = 0; r < 16; r++) {
        int prow = tq * 16 + r;
        xt[(pbase + prow) * 256 + cbase + tx] = f2b(tile[tx][prow]);
    }
}

// ---------- QKV projection: C[768][2304] = Wall[0:768] @ x ; scatter to Qf/Kf/Vt
// Qf[n][64] bf16 (pre-scaled QSCALE), Kf[n][64] bf16, Vt[64][9216] bf16, n = p*4+h
__global__ __launch_bounds__(256) void k_gemm_qkv(
    const short* __restrict__ Wall, const short* __restrict__ xt,
    const float* __restrict__ bq, const float* __restrict__ bk, const float* __restrict__ bv,
    short* __restrict__ Qf, short* __restrict__ Kf, short* __restrict__ Vt) {
    int t = threadIdx.x, wave = t >> 6, lane = t & 63, lr = lane & 15, lg = lane >> 4;
    int obase = blockIdx.x * 64 + wave * 16;   // grid.x = 12
    int pbase = blockIdx.y * 64;               // grid.y = 36
    const short* arow  = Wall + (obase + lr) * 256 + lg * 8;
    const short* brow0 = xt + (pbase +  0 + lr) * 256 + lg * 8;
    const short* brow1 = xt + (pbase + 16 + lr) * 256 + lg * 8;
    const short* brow2 = xt + (pbase + 32 + lr) * 256 + lg * 8;
    const short* brow3 = xt + (pbase + 48 + lr) * 256 + lg * 8;
    f32x4 acc0 = {0,0,0,0}, acc1 = {0,0,0,0}, acc2 = {0,0,0,0}, acc3 = {0,0,0,0};
    #pragma unroll
    for (int ks = 0; ks < 8; ks++) {
        bf16x8 a = *(const bf16x8*)(arow + ks * 32);
        acc0 = MFMA(a, *(const bf16x8*)(brow0 + ks * 32), acc0);
        acc1 = MFMA(a, *(const bf16x8*)(brow1 + ks * 32), acc1);
        acc2 = MFMA(a, *(const bf16x8*)(brow2 + ks * 32), acc2);
        acc3 = MFMA(a, *(const bf16x8*)(brow3 + ks * 32), acc3);
    }
    int w_idx = obase >> 8;  // 0=q 1=k 2=v, uniform per block
    const float* bias = (w_idx == 0) ? bq : (w_idx == 1) ? bk : bv;
    f32x4 accs[4] = {acc0, acc1, acc2, acc3};
    #pragma unroll
    for (int i = 0; i < 4; i++) {
        int o = obase + 4 * lg + i;
        int oo = o & 255;
        float b = bias[oo];
        int h = oo >> 6, d = oo & 63;
        #pragma unroll
        for (int ct = 0; ct < 4; ct++) {
            int p = pbase + ct * 16 + lr;
            float val = accs[ct][i] + b;
            int n = p * 4 + h;
            if (w_idx == 0)      Qf[n * 64 + d] = f2b(val * QSCALE);
            else if (w_idx == 1) Kf[n * 64 + d] = f2b(val);
            else                 Vt[d * 9216 + n] = f2b(val);
        }
    }
}

// ---------- flash attention: N=9216, d=64. Grid (144 qblocks, nsplit kvchunks).
// Block = 2 waves x 128 thr = 64 queries; wave owns 32 (two 16-q groups A/B at
// qA = bx*64 + w*16, qB = qA+32). Each K/V LDS tile (64 keys) is read ONCE per
// wave and feeds both q-groups -> LDS reads per score halved vs r7.
// K [64][64] + V [64dv][64k] staged via global_load_lds (double-buffered),
// FSW slot-swizzle (measured 0 bank conflicts in r7; write-side inverse swizzle
// verified: FSW(srow)=(sr&3)|((c&1)<<2) matches read-side FSW for all rows).
// Log2-domain softmax (Qf pre-scaled QSCALE), defer-max THR=11, cvt_pk P-pack.
// Swapped QK^T (mfma(K,Q)=S^T, perm'd rows) => st regs are the PV B-frag.
__global__ __launch_bounds__(128) void k_attn(
    const short* __restrict__ Qf, const short* __restrict__ Kf,
    const short* __restrict__ Vt, int keysPer, int ntiles,
    float* __restrict__ pm, float* __restrict__ ps, float* __restrict__ pacc) {
    __shared__ short ktile[2][4096];   // [buf][64 keys][64 d], slot-swizzled
    __shared__ short vtile[2][4096];   // [buf][64 dv][64 keys], slot-swizzled
    int t = threadIdx.x, wave = t >> 6, lane = t & 63, lr = lane & 15, lg = lane >> 4;
    int kb = blockIdx.y;
    int qA = blockIdx.x * 64 + wave * 16;      // grid.x = 144
    int kstart = kb * keysPer;

    const short* qrowA = Qf + (qA + lr) * 64 + lg * 8;
    bf16x8 q0 = *(const bf16x8*)(qrowA);
    bf16x8 q1 = *(const bf16x8*)(qrowA + 32);
    const short* qrowB = qrowA + 32 * 64;      // qB = qA + 32
    bf16x8 q2 = *(const bf16x8*)(qrowB);
    bf16x8 q3 = *(const bf16x8*)(qrowB + 32);

    bf16x8 ones;
    #pragma unroll
    for (int i = 0; i < 8; i++) ones[i] = (short)0x3F80;   // bf16 1.0

    // ---- staging: wave stages rows wave*32..+31 of K and V (4 calls each)
    int sr = lane >> 3, slot = lane & 7;
    int colE = (slot ^ (sr & 3)) << 4;         // calls c even: FSW = sr&3
    int colO = (slot ^ ((sr & 3) | 4)) << 4;   // calls c odd : FSW = (sr&3)|4
    const char* kS = (const char*)Kf + (size_t)(kstart + wave * 32 + sr) * 128;
    const char* vS = (const char*)Vt + (size_t)(wave * 32 + sr) * 18432 + (size_t)kstart * 2;
    short* kD[2] = { &ktile[0][wave * 2048], &ktile[1][wave * 2048] };
    short* vD[2] = { &vtile[0][wave * 2048], &vtile[1][wave * 2048] };

    // ---- ds_read byte offsets (tile-relative; FSW applied on read side)
    int perm = (lr & 3) + 8 * (lr >> 2);   // K-row perm: st regs -> keys 8*lg+i
    int cb = lg * 16;
    int kOffA0 = perm * 128       + (cb        ^ (FSW(perm) << 4));
    int kOffA1 = perm * 128       + ((cb + 64) ^ (FSW(perm) << 4));
    int kOffB0 = (perm + 4) * 128 + (cb        ^ (FSW(perm + 4) << 4));
    int kOffB1 = (perm + 4) * 128 + ((cb + 64) ^ (FSW(perm + 4) << 4));
    int vOff   = lr * 128         + (cb        ^ (FSW(lr) << 4));
    // V rows lr+16k share FSW(lr); +16 rows = +2048B. 2nd key-half = ^64.

    float mA = -1e30f, mB = -1e30f;
    f32x4 zv = {0,0,0,0};
    f32x4 accA0 = zv, accA1 = zv, accA2 = zv, accA3 = zv, saccA = zv;
    f32x4 accB0 = zv, accB1 = zv, accB2 = zv, accB3 = zv, saccB = zv;

    // prologue: stage tile 0 into buf 0
    #pragma unroll
    for (int c = 0; c < 4; c++) {
        int col = (c & 1) ? colO : colE;
        stage16(kS + c * 1024 + col, kD[0] + c * 512);
        stage16(vS + (size_t)c * 8 * 18432 + col, vD[0] + c * 512);
    }

    for (int tt = 0; tt < ntiles; tt++) {
        __syncthreads();                 // drain -> tile tt staged for all waves
        int buf = tt & 1;
        if (tt + 1 < ntiles) {
            size_t ko = (size_t)(tt + 1) * 8192, vo = (size_t)(tt + 1) * 128;
            #pragma unroll
            for (int c = 0; c < 4; c++) {
                int col = (c & 1) ? colO : colE;
                stage16(kS + ko + c * 1024 + col, kD[buf ^ 1] + c * 512);
                stage16(vS + vo + (size_t)c * 8 * 18432 + col, vD[buf ^ 1] + c * 512);
            }
        }
        const char* kt = (const char*)&ktile[buf][0];
        const char* vt = (const char*)&vtile[buf][0];

        // ---- QK^T (S^T), key half 0 (keys 0..31), both q-groups
        bf16x8 kA0 = *(const bf16x8*)(kt + kOffA0);
        bf16x8 kA1 = *(const bf16x8*)(kt + kOffA1);
        bf16x8 kB0 = *(const bf16x8*)(kt + kOffB0);
        bf16x8 kB1 = *(const bf16x8*)(kt + kOffB1);
        f32x4 sA0 = MFMA(kA0, q0, zv); sA0 = MFMA(kA1, q1, sA0);
        f32x4 sA1 = MFMA(kB0, q0, zv); sA1 = MFMA(kB1, q1, sA1);
        f32x4 sB0 = MFMA(kA0, q2, zv); sB0 = MFMA(kA1, q3, sB0);
        f32x4 sB1 = MFMA(kB0, q2, zv); sB1 = MFMA(kB1, q3, sB1);
        // ---- key half 1 (keys 32..63)
        kA0 = *(const bf16x8*)(kt + 4096 + kOffA0);
        kA1 = *(const bf16x8*)(kt + 4096 + kOffA1);
        kB0 = *(const bf16x8*)(kt + 4096 + kOffB0);
        kB1 = *(const bf16x8*)(kt + 4096 + kOffB1);
        f32x4 sA2 = MFMA(kA0, q0, zv); sA2 = MFMA(kA1, q1, sA2);
        f32x4 sA3 = MFMA(kB0, q0, zv); sA3 = MFMA(kB1, q1, sA3);
        f32x4 sB2 = MFMA(kA0, q2, zv); sB2 = MFMA(kA1, q3, sB2);
        f32x4 sB3 = MFMA(kB0, q2, zv); sB3 = MFMA(kB1, q3, sB3);

        // ---- merged 64-key max per group (log2 domain)
        float tmA = fmaxf(
            fmaxf(fmaxf(fmaxf(sA0[0], sA0[1]), fmaxf(sA0[2], sA0[3])),
                  fmaxf(fmaxf(sA1[0], sA1[1]), fmaxf(sA1[2], sA1[3]))),
            fmaxf(fmaxf(fmaxf(sA2[0], sA2[1]), fmaxf(sA2[2], sA2[3])),
                  fmaxf(fmaxf(sA3[0], sA3[1]), fmaxf(sA3[2], sA3[3]))));
        float tmB = fmaxf(
            fmaxf(fmaxf(fmaxf(sB0[0], sB0[1]), fmaxf(sB0[2], sB0[3])),
                  fmaxf(fmaxf(sB1[0], sB1[1]), fmaxf(sB1[2], sB1[3]))),
            fmaxf(fmaxf(fmaxf(sB2[0], sB2[1]), fmaxf(sB2[2], sB2[3])),
                  fmaxf(fmaxf(sB3[0], sB3[1]), fmaxf(sB3[2], sB3[3]))));
        tmA = fmaxf(fmaxf(tmA, __shfl_xor(tmA, 16)),
                    fmaxf(__shfl_xor(tmA, 32), __shfl_xor(tmA, 48)));
        tmB = fmaxf(fmaxf(tmB, __shfl_xor(tmB, 16)),
                    fmaxf(__shfl_xor(tmB, 32), __shfl_xor(tmB, 48)));
        if (!__all((tmA - mA <= 11.0f) && (tmB - mB <= 11.0f))) {  // defer-max
            float mnA = fmaxf(mA, tmA), mnB = fmaxf(mB, tmB);
            float scA = ex2(mA - mnA), scB = ex2(mB - mnB);
            accA0 *= scA; accA1 *= scA; accA2 *= scA; accA3 *= scA; saccA *= scA;
            accB0 *= scB; accB1 *= scB; accB2 *= scB; accB3 *= scB; saccB *= scB;
            mA = mnA; mB = mnB;
        }
        union { uint32_t w[4]; bf16x8 v; } paA, pbA, paB, pbB;
        paA.w[0] = cvtpk(ex2(sA0[0] - mA), ex2(sA0[1] - mA));
        paA.w[1] = cvtpk(ex2(sA0[2] - mA), ex2(sA0[3] - mA));
        paA.w[2] = cvtpk(ex2(sA1[0] - mA), ex2(sA1[1] - mA));
        paA.w[3] = cvtpk(ex2(sA1[2] - mA), ex2(sA1[3] - mA));
        pbA.w[0] = cvtpk(ex2(sA2[0] - mA), ex2(sA2[1] - mA));
        pbA.w[1] = cvtpk(ex2(sA2[2] - mA), ex2(sA2[3] - mA));
        pbA.w[2] = cvtpk(ex2(sA3[0] - mA), ex2(sA3[1] - mA));
        pbA.w[3] = cvtpk(ex2(sA3[2] - mA), ex2(sA3[3] - mA));
        paB.w[0] = cvtpk(ex2(sB0[0] - mB), ex2(sB0[1] - mB));
        paB.w[1] = cvtpk(ex2(sB0[2] - mB), ex2(sB0[3] - mB));
        paB.w[2] = cvtpk(ex2(sB1[0] - mB), ex2(sB1[1] - mB));
        paB.w[3] = cvtpk(ex2(sB1[2] - mB), ex2(sB1[3] - mB));
        pbB.w[0] = cvtpk(ex2(sB2[0] - mB), ex2(sB2[1] - mB));
        pbB.w[1] = cvtpk(ex2(sB2[2] - mB), ex2(sB2[3] - mB));
        pbB.w[2] = cvtpk(ex2(sB3[0] - mB), ex2(sB3[1] - mB));
        pbB.w[3] = cvtpk(ex2(sB3[2] - mB), ex2(sB3[3] - mB));

        // ---- PV over both key halves + denominators (V frags shared A/B)
        bf16x8 v0a = *(const bf16x8*)(vt + vOff);
        bf16x8 v0b = *(const bf16x8*)(vt + (vOff ^ 64));
        bf16x8 v1a = *(const bf16x8*)(vt + vOff + 2048);
        bf16x8 v1b = *(const bf16x8*)(vt + ((vOff + 2048) ^ 64));
        bf16x8 v2a = *(const bf16x8*)(vt + vOff + 4096);
        bf16x8 v2b = *(const bf16x8*)(vt + ((vOff + 4096) ^ 64));
        bf16x8 v3a = *(const bf16x8*)(vt + vOff + 6144);
        bf16x8 v3b = *(const bf16x8*)(vt + ((vOff + 6144) ^ 64));
        accA0 = MFMA(v0a, paA.v, accA0); accA0 = MFMA(v0b, pbA.v, accA0);
        accA1 = MFMA(v1a, paA.v, accA1); accA1 = MFMA(v1b, pbA.v, accA1);
        accA2 = MFMA(v2a, paA.v, accA2); accA2 = MFMA(v2b, pbA.v, accA2);
        accA3 = MFMA(v3a, paA.v, accA3); accA3 = MFMA(v3b, pbA.v, accA3);
        saccA = MFMA(ones, paA.v, saccA); saccA = MFMA(ones, pbA.v, saccA);
        accB0 = MFMA(v0a, paB.v, accB0); accB0 = MFMA(v0b, pbB.v, accB0);
        accB1 = MFMA(v1a, paB.v, accB1); accB1 = MFMA(v1b, pbB.v, accB1);
        accB2 = MFMA(v2a, paB.v, accB2); accB2 = MFMA(v2b, pbB.v, accB2);
        accB3 = MFMA(v3a, paB.v, accB3); accB3 = MFMA(v3b, pbB.v, accB3);
        saccB = MFMA(ones, paB.v, saccB); saccB = MFMA(ones, pbB.v, saccB);
    }

    // ---- per-wave partial out (two 16-q groups)
    int gA = blockIdx.x * 4 + wave;          // group of qA
    int gB = gA + 2;                         // group of qB (qA+32)
    int pidxA = kb * 576 + gA, pidxB = kb * 576 + gB;
    float* paOutA = pacc + (size_t)pidxA * 1024 + lr * 64 + lg * 4;
    *(f32x4*)(paOutA +  0) = accA0;
    *(f32x4*)(paOutA + 16) = accA1;
    *(f32x4*)(paOutA + 32) = accA2;
    *(f32x4*)(paOutA + 48) = accA3;
    float* paOutB = pacc + (size_t)pidxB * 1024 + lr * 64 + lg * 4;
    *(f32x4*)(paOutB +  0) = accB0;
    *(f32x4*)(paOutB + 16) = accB1;
    *(f32x4*)(paOutB + 32) = accB2;
    *(f32x4*)(paOutB + 48) = accB3;
    if (lg == 0) {                       // sacc[0] = s[q=lr]
        pm[pidxA * 16 + lr] = mA;  ps[pidxA * 16 + lr] = saccA[0];
        pm[pidxB * 16 + lr] = mB;  ps[pidxB * 16 + lr] = saccB[0];
    }
}

// ---------- combine nsplit KV-chunk partials -> Of bf16 [2304][256]
__global__ __launch_bounds__(256) void k_attn_combine(
    const float* __restrict__ pm, const float* __restrict__ ps,
    const float* __restrict__ pacc, short* __restrict__ Of, int nsplit) {
    int qb = blockIdx.x, t = threadIdx.x;   // grid = 576; thread owns one f32x4
    int q = t >> 4, dv4 = (t & 15) * 4;
    float mg = -1e30f;
    for (int s = 0; s < nsplit; s++)
        mg = fmaxf(mg, pm[(s * 576 + qb) * 16 + q]);
    float S = 0.f;
    f32x4 O = {0, 0, 0, 0};
    for (int s = 0; s < nsplit; s++) {
        float e = ex2(pm[(s * 576 + qb) * 16 + q] - mg);   // log2 domain
        S += ps[(s * 576 + qb) * 16 + q] * e;
        f32x4 pv = *(const f32x4*)(pacc + (size_t)(s * 576 + qb) * 1024 + q * 64 + dv4);
        O += pv * e;
    }
    float inv = 1.0f / S;
    uint32_t w0 = cvtpk(O[0] * inv, O[1] * inv);
    uint32_t w1 = cvtpk(O[2] * inv, O[3] * inv);
    int n = qb * 16 + q, p = n >> 2, hh = n & 3;
    uint2 pk; pk.x = w0; pk.y = w1;
    *(uint2*)(&Of[p * 256 + hh * 64 + dv4]) = pk;
}

// ---------- output projection: out[256][2304] = Wo @ Of^T + bo (fp32 out, NCHW)
__global__ __launch_bounds__(256) void k_gemm_out(
    const short* __restrict__ Wo_bf, const short* __restrict__ Of,
    const float* __restrict__ bo, float* __restrict__ out) {
    int t = threadIdx.x, wave = t >> 6, lane = t & 63, lr = lane & 15, lg = lane >> 4;
    int obase = blockIdx.x * 64 + wave * 16;   // grid.x = 4
    int pbase = blockIdx.y * 64;               // grid.y = 36
    const short* arow  = Wo_bf + (obase + lr) * 256 + lg * 8;
    const short* brow0 = Of + (pbase +  0 + lr) * 256 + lg * 8;
    const short* brow1 = Of + (pbase + 16 + lr) * 256 + lg * 8;
    const short* brow2 = Of + (pbase + 32 + lr) * 256 + lg * 8;
    const short* brow3 = Of + (pbase + 48 + lr) * 256 + lg * 8;
    f32x4 acc0 = {0,0,0,0}, acc1 = {0,0,0,0}, acc2 = {0,0,0,0}, acc3 = {0,0,0,0};
    #pragma unroll
    for (int ks = 0; ks < 8; ks++) {
        bf16x8 a = *(const bf16x8*)(arow + ks * 32);
        acc0 = MFMA(a, *(const bf16x8*)(brow0 + ks * 32), acc0);
        acc1 = MFMA(a, *(const bf16x8*)(brow1 + ks * 32), acc1);
        acc2 = MFMA(a, *(const bf16x8*)(brow2 + ks * 32), acc2);
        acc3 = MFMA(a, *(const bf16x8*)(brow3 + ks * 32), acc3);
    }
    f32x4 accs[4] = {acc0, acc1, acc2, acc3};
    #pragma unroll
    for (int i = 0; i < 4; i++) {
        int o = obase + 4 * lg + i;
        float b = bo[o];
        #pragma unroll
        for (int ct = 0; ct < 4; ct++) {
            int p = pbase + ct * 16 + lr;
            out[o * 2304 + p] = accs[ct][i] + b;
        }
    }
}

extern "C" void kernel_launch(void* const* d_in, const int* in_sizes, int n_in,
                              void* d_out, int out_size, void* d_ws, size_t ws_size,
                              hipStream_t stream) {
    const float* x  = (const float*)d_in[0];
    const float* Wq = (const float*)d_in[1];
    const float* bq = (const float*)d_in[2];
    const float* Wk = (const float*)d_in[3];
    const float* bk = (const float*)d_in[4];
    const float* Wv = (const float*)d_in[5];
    const float* bv = (const float*)d_in[6];
    const float* Wo = (const float*)d_in[7];
    const float* bo = (const float*)d_in[8];

    char* ws = (char*)d_ws;
    short* Wall = (short*)(ws);                     // 1024*256*2 = 524288 B
    short* xt   = (short*)(ws + 524288);            // 2304*256*2
    short* Qf   = (short*)(ws + 1703936);           // 9216*64*2
    short* Kf   = (short*)(ws + 2883584);           // 9216*64*2
    short* Vt   = (short*)(ws + 4063232);           // 64*9216*2
    short* Of   = (short*)(ws + 5242880);           // 2304*256*2 (ends 6422528)
    float* pm   = (float*)(ws + 6422528);           // 8*576*16*4 = 294912 max
    float* ps   = (float*)(ws + 6717440);           // 294912 max
    float* pacc = (float*)(ws + 7012352);           // nsplit*576*1024*4
    float* out  = (float*)d_out;

    // nsplit=8 needs ws end ~25.9MB; fall back to 4 (16.4MB) if ws is small
    int nsplit = (ws_size >= (size_t)7012352 + 8u * 2359296u) ? 8 : 4;
    int keysPer = 9216 / nsplit;
    int ntiles = keysPer / 64;

    k_cast_w<<<1024, 256, 0, stream>>>(Wq, Wk, Wv, Wo, Wall);
    k_transpose_x<<<dim3(36, 4), 256, 0, stream>>>(x, xt);
    k_gemm_qkv<<<dim3(12, 36), 256, 0, stream>>>(Wall, xt, bq, bk, bv, Qf, Kf, Vt);
    k_attn<<<dim3(144, nsplit), 128, 0, stream>>>(Qf, Kf, Vt, keysPer, ntiles, pm, ps, pacc);
    k_attn_combine<<<576, 256, 0, stream>>>(pm, ps, pacc, Of, nsplit);
    k_gemm_out<<<dim3(4, 36), 256, 0, stream>>>(Wall + 768 * 256, Of, bo, out);
}